// Round 14
// baseline (69.779 us; speedup 1.0000x reference)
//
#include <hip/hip_runtime.h>
#include <stdint.h>
#include <math.h>

#define BB 4
#define HH 512
#define WW 512
#define HWW (HH*WW)      // 262144
#define CC 128
#define KK 512
#define SELCAP 2048
#define NBIN 8192
#define NPADK 512

#define TILE 32          // 32x32 output tile -> 2 blocks/CU
#define HALO 15
#define TS 62            // TILE + 2*HALO
#define SWL 72           // stride: 4 front pad + 62 + tail, f4-aligned
#define NT 1024
#define NSEG 256         // tiles per batch (16x16)
#define TCAP 128         // per-tile candidate slots (max real 81)

typedef unsigned int uint;
typedef unsigned long long u64;

__device__ __forceinline__ float4 ldsf4(const float* p, int o){ return *(const float4*)(p + o); }

#define COLMAX7V(src, o, cm)                                                  \
    { float4 c0=ldsf4(src,(o)-3*SWL), c1=ldsf4(src,(o)-2*SWL), c2=ldsf4(src,(o)-SWL), \
             c3=ldsf4(src,(o)),       c4=ldsf4(src,(o)+SWL),   c5=ldsf4(src,(o)+2*SWL), \
             c6=ldsf4(src,(o)+3*SWL);                                         \
      cm.x=fmaxf(fmaxf(fmaxf(c0.x,c1.x),fmaxf(c2.x,c3.x)),fmaxf(fmaxf(c4.x,c5.x),c6.x)); \
      cm.y=fmaxf(fmaxf(fmaxf(c0.y,c1.y),fmaxf(c2.y,c3.y)),fmaxf(fmaxf(c4.y,c5.y),c6.y)); \
      cm.z=fmaxf(fmaxf(fmaxf(c0.z,c1.z),fmaxf(c2.z,c3.z)),fmaxf(fmaxf(c4.z,c5.z),c6.z)); \
      cm.w=fmaxf(fmaxf(fmaxf(c0.w,c1.w),fmaxf(c2.w,c3.w)),fmaxf(fmaxf(c4.w,c5.w),c6.w)); }

#define ROWMAXV(dst, src, Y0, NROW, G0, NG)                                   \
    for (int i = tid; i < (NROW)*(NG); i += NT){                              \
        int y = (Y0) + i/(NG);                                                \
        int o = y*SWL + (G0) + 4*(i%(NG)) + 4;                                \
        float4 va = ldsf4(src, o-4), vb = ldsf4(src, o), vc = ldsf4(src, o+4);\
        float m2a=fmaxf(va.y,va.z), m2b=fmaxf(va.w,vb.x), m2c=fmaxf(vb.y,vb.z),\
              m2d=fmaxf(vb.w,vc.x), m2e=fmaxf(vc.y,vc.z);                     \
        float4 r;                                                             \
        r.x = fmaxf(fmaxf(m2a,m2b), fmaxf(m2c, vb.w));                        \
        r.y = fmaxf(fmaxf(va.z,m2b), fmaxf(m2c, m2d));                        \
        r.z = fmaxf(fmaxf(m2b,m2c), fmaxf(m2d, vc.y));                        \
        r.w = fmaxf(fmaxf(vb.x,m2c), fmaxf(m2d, m2e));                        \
        *(float4*)((dst) + o) = r;                                            \
    }                                                                         \
    __syncthreads();

#define ROWORV(dst, src, Y0, NROW, G0, NG)                                    \
    for (int i = tid; i < (NROW)*(NG); i += NT){                              \
        int y = (Y0) + i/(NG);                                                \
        int o = y*SWL + (G0) + 4*(i%(NG)) + 4;                                \
        uint u0 = *(const uint*)((src)+o-4), u1 = *(const uint*)((src)+o),    \
             u2 = *(const uint*)((src)+o+4);                                  \
        u64 lo = (u64)u0 | ((u64)u1 << 32);                                   \
        uint r = (uint)(lo>>8) | (uint)(lo>>16) | (uint)(lo>>24) | (uint)(lo>>32) \
               | ((uint)(lo>>40)|(u2<<24)) | ((uint)(lo>>48)|(u2<<16))        \
               | ((uint)(lo>>56)|(u2<<8));                                    \
        *(uint*)((dst)+o) = r;                                                \
    }                                                                         \
    __syncthreads();

#define COLSUPPV(Y0, NROW, G0, NG)                                            \
    for (int i = tid; i < (NROW)*(NG); i += NT){                              \
        int y = (Y0) + i/(NG);                                                \
        int o = y*SWL + (G0) + 4*(i%(NG)) + 4;                                \
        uint v = *(const uint*)(T+o-3*SWL) | *(const uint*)(T+o-2*SWL)        \
               | *(const uint*)(T+o-SWL)   | *(const uint*)(T+o)              \
               | *(const uint*)(T+o+SWL)   | *(const uint*)(T+o+2*SWL)        \
               | *(const uint*)(T+o+3*SWL);                                   \
        *(uint*)(P + o) = v;                                                  \
        float4 s4 = ldsf4(S, o);                                              \
        float4 a;                                                             \
        a.x = (v & 0xffu)       ? 0.0f : s4.x;                                \
        a.y = (v & 0xff00u)     ? 0.0f : s4.y;                                \
        a.z = (v & 0xff0000u)   ? 0.0f : s4.z;                                \
        a.w = (v & 0xff000000u) ? 0.0f : s4.w;                                \
        *(float4*)(A + o) = a;                                                \
    }                                                                         \
    __syncthreads();

// One block = one 32x32 tile (+15 halo), 68 KB LDS -> 2 blocks/CU.
// Pass ranges derived for TS=62 (valid col range shrinks 64->61->58->55->52,
// final reads lds_x [19,51) only; garbage fringe proven non-propagating).
__global__ __launch_bounds__(NT, 8) void nms_fused_k(const float* __restrict__ sc,
        float* __restrict__ cs, int* __restrict__ ci, int* __restrict__ cnt){
    __shared__ __align__(16) float S[TS*SWL];
    __shared__ __align__(16) float A[TS*SWL];
    __shared__ __align__(16) float Bf[TS*SWL];
    __shared__ __align__(16) unsigned char M[TS*SWL];
    __shared__ __align__(16) unsigned char T[TS*SWL];
    __shared__ __align__(16) unsigned char P[TS*SWL];
    __shared__ float lsc[TCAP];
    __shared__ int   lidx[TCAP];
    __shared__ int   lcnt;

    const int tid = threadIdx.x;
    const int bb = blockIdx.x >> 8;          // batch
    const int t  = blockIdx.x & 255;         // tile in 16x16 grid
    const int ty = t >> 4, tx = t & 15;
    const int oy = ty * TILE - HALO, ox = tx * TILE - HALO;
    const float* sb = sc + (size_t)bb * HWW;
    const float QNAN = __int_as_float(0x7fc00000);

    if (tid == 0) lcnt = 0;

    // load: image x = ox + lds_x - 4; out-of-image = NaN
    for (int i = tid; i < TS*SWL; i += NT){
        int y = i / SWL, x = i - y*SWL;
        int gy = oy + y, gx = ox + x - 4;
        float v = QNAN;
        if ((unsigned)gy < (unsigned)HH && (unsigned)gx < (unsigned)WW)
            v = sb[(gy << 9) + gx];
        S[i] = v;
    }
    __syncthreads();

    // M0 = (s == pool7(s))
    ROWMAXV(A, S, 0, 62, 0, 15)
    for (int i = tid; i < 56*15; i += NT){
        int y = 3 + i/15;
        int o = y*SWL + 4*(i%15) + 4;
        float4 cm; COLMAX7V(A, o, cm);
        float4 s4 = ldsf4(S, o);
        uint m = (s4.x==cm.x ?1u:0u) | (s4.y==cm.y ?0x100u:0u)
               | (s4.z==cm.z ?0x10000u:0u) | (s4.w==cm.w ?0x1000000u:0u);
        *(uint*)(M + o) = m;
    }
    __syncthreads();

    // iteration 1
    ROWORV(T, M, 3, 56, 4, 14)
    COLSUPPV(6, 50, 4, 14)
    ROWMAXV(Bf, A, 6, 50, 8, 13)
    for (int i = tid; i < 44*13; i += NT){
        int y = 9 + i/13;
        int o = y*SWL + 8 + 4*(i%13) + 4;
        float4 cm; COLMAX7V(Bf, o, cm);
        float4 a4 = ldsf4(A, o);
        uint p4 = *(const uint*)(P+o);
        uint nm = (a4.x==cm.x ?1u:0u)|(a4.y==cm.y ?0x100u:0u)
                | (a4.z==cm.z ?0x10000u:0u)|(a4.w==cm.w ?0x1000000u:0u);
        uint m4 = *(const uint*)(M+o);
        *(uint*)(M+o) = m4 | (nm & ~p4);
    }
    __syncthreads();

    // iteration 2
    ROWORV(T, M, 9, 44, 12, 12)
    COLSUPPV(12, 38, 12, 12)
    ROWMAXV(Bf, A, 12, 38, 12, 12)

    // final mask + compaction (rows [15,47), lds_x [19,51) via guard)
    for (int i = tid; i < 32*9; i += NT){
        int y = 15 + i/9;
        int xg = 12 + 4*(i%9);
        int o = y*SWL + xg + 4;
        float4 cm; COLMAX7V(Bf, o, cm);
        float4 a4 = ldsf4(A, o), s4 = ldsf4(S, o);
        uint p4 = *(const uint*)(P+o), m4 = *(const uint*)(M+o);
        float sa[4] = {s4.x, s4.y, s4.z, s4.w};
        float aa[4] = {a4.x, a4.y, a4.z, a4.w};
        float ca[4] = {cm.x, cm.y, cm.z, cm.w};
        #pragma unroll
        for (int j = 0; j < 4; ++j){
            int x = xg + j;                  // pre-pad coord; image x = ox + x
            bool fm = ((m4 >> (8*j)) & 1u) || ((aa[j]==ca[j]) && !((p4 >> (8*j)) & 1u));
            if ((unsigned)(x - 15) < (unsigned)TILE && fm && sa[j] > 0.0f){
                int p = atomicAdd(&lcnt, 1);
                if (p < TCAP){ lsc[p] = sa[j]; lidx[p] = ((oy+y) << 9) + (ox+x); }
            }
        }
    }
    __syncthreads();

    int nl = lcnt; if (nl > TCAP) nl = TCAP;
    const int seg = bb * NSEG + t;
    if (tid == 0) cnt[seg] = nl;
    float* os = cs + (size_t)seg * TCAP;
    int*   oi = ci + (size_t)seg * TCAP;
    for (int i = tid; i < nl; i += NT){ os[i] = lsc[i]; oi[i] = lidx[i]; }
}

// ---------- fused select+gather v3 (fixed-point histogram; 256 segs x 128) ----------

__device__ __forceinline__ uint fxbin(float v){
    return ((uint)(v * 8388608.0f)) >> 10;      // exact for v in (0,1)
}

__global__ __launch_bounds__(NT) void selgather_k(
        const float* __restrict__ cs, const int* __restrict__ ci, const int* __restrict__ cnt,
        const float* __restrict__ pts, const float* __restrict__ feat,
        float* __restrict__ out){
    __shared__ int  hist[NBIN];
    __shared__ __align__(16) u64 keys[SELCAP + 4];
    __shared__ int  segc[NSEG];
    __shared__ int  wsum[16];
    __shared__ int  sidx[KK];
    __shared__ uint sh_Tbits;
    __shared__ int  sh_bin, sh_kneed, sh_n, selCnt, bcnt;

    const int blk = blockIdx.x;
    const int b = blk >> 6, slice = blk & 63;
    const int tid = threadIdx.x;
    const int wv = tid >> 6, lane = tid & 63;

    {
        int4* h4 = (int4*)hist;
        for (int i = tid; i < NBIN/4; i += NT) h4[i] = make_int4(0,0,0,0);
    }
    if (tid < NSEG){ int c = cnt[b*NSEG + tid]; segc[tid] = (c > TCAP) ? TCAP : c; }
    if (tid == 0){ selCnt = 0; bcnt = 0; sh_Tbits = 1u; }
    __syncthreads();

    // P1: histogram (wave wv owns segments 16wv..16wv+15)
    #pragma unroll
    for (int ss = 0; ss < 16; ++ss){
        int s = wv*16 + ss;
        int c = segc[s];
        const float* ps = cs + (size_t)(b*NSEG + s) * TCAP;
        for (int i = lane; i < c; i += 64)
            atomicAdd(&hist[fxbin(ps[i])], 1);
    }
    __syncthreads();

    // P2: suffix scan over 8192 bins; boundary bin + kneed
    int hh[8];
    {
        int4 h0 = *(int4*)&hist[tid*8], h1 = *(int4*)&hist[tid*8 + 4];
        hh[0]=h0.x; hh[1]=h0.y; hh[2]=h0.z; hh[3]=h0.w;
        hh[4]=h1.x; hh[5]=h1.y; hh[6]=h1.z; hh[7]=h1.w;
    }
    int s8 = hh[0]+hh[1]+hh[2]+hh[3]+hh[4]+hh[5]+hh[6]+hh[7];
    int suf = s8;
    #pragma unroll
    for (int off = 1; off < 64; off <<= 1){
        int v = __shfl_down(suf, off);
        if (lane + off < 64) suf += v;
    }
    if (lane == 0) wsum[wv] = suf;
    __syncthreads();
    int W = 0, tot = 0;
    #pragma unroll
    for (int w2 = 0; w2 < 16; ++w2){ int v = wsum[w2]; tot += v; if (w2 > wv) W += v; }
    if (tid == 0) sh_n = tot;
    int G = W + (suf - s8);
    if (tot >= KK && G < KK && G + s8 >= KK){
        int cum = G;
        #pragma unroll
        for (int k = 7; k >= 0; --k){
            if (cum + hh[k] >= KK){ sh_bin = tid*8 + k; sh_kneed = KK - cum; break; }
            cum += hh[k];
        }
    }
    __syncthreads();
    const int n = sh_n;

    uint Tbits = 1u;
    if (n >= KK){
        const int bstar = sh_bin, kneed = sh_kneed;
        // P3: collect boundary-bin members
        #pragma unroll
        for (int ss = 0; ss < 16; ++ss){
            int s = wv*16 + ss;
            int c = segc[s];
            const float* ps = cs + (size_t)(b*NSEG + s) * TCAP;
            for (int i = lane; i < c; i += 64){
                float v = ps[i];
                if ((int)fxbin(v) == bstar){
                    int p = atomicAdd(&bcnt, 1);
                    if (p < SELCAP) keys[p] = (u64)__float_as_uint(v);
                }
            }
        }
        __syncthreads();
        // P4: kneed-th largest among boundary members
        int m = bcnt; if (m > SELCAP) m = SELCAP;
        if (tid < m){
            u64 mine = keys[tid];
            int gt = 0, ge = 0;
            for (int j = 0; j < m; ++j){
                u64 v = keys[j];
                gt += (v > mine) ? 1 : 0;
                ge += (v >= mine) ? 1 : 0;
            }
            if (gt < kneed && kneed <= ge) sh_Tbits = (uint)mine;
        }
        __syncthreads();
        Tbits = sh_Tbits;
    }

    // P5: final collect (ballot-aggregated)
    #pragma unroll
    for (int ss = 0; ss < 16; ++ss){
        int s = wv*16 + ss;
        int c = segc[s];
        const float* ps = cs + (size_t)(b*NSEG + s) * TCAP;
        const int*   pi = ci + (size_t)(b*NSEG + s) * TCAP;
        for (int i0 = 0; i0 < c; i0 += 64){
            int i = i0 + lane;
            bool hit = false; uint bits = 0;
            if (i < c){ bits = __float_as_uint(ps[i]); hit = (bits >= Tbits); }
            u64 m = __ballot(hit);
            if (!m) continue;
            int wbase = 0;
            if (lane == 0) wbase = atomicAdd(&selCnt, (int)__popcll(m));
            wbase = __shfl(wbase, 0);
            if (hit){
                int p = wbase + (int)__popcll(m & ((1ull << lane) - 1ull));
                if (p < SELCAP) keys[p] = ((u64)bits << 32) | (uint)(~pi[i]);
            }
        }
    }
    __syncthreads();
    int ns = selCnt; if (ns > SELCAP) ns = SELCAP;
    for (int i = ns + tid; i < NPADK; i += NT) keys[i] = 0ull;
    __syncthreads();

    // P6: rank-by-count
    if (ns <= NPADK){
        u64 ck[8];
        #pragma unroll
        for (int r = 0; r < 8; ++r) ck[r] = keys[r*64 + lane];
        for (int t0 = 0; t0 < 32; ++t0){
            int t = wv*32 + t0;
            u64 my = keys[t];
            int c = 0;
            #pragma unroll
            for (int r = 0; r < 8; ++r) c += (ck[r] > my) ? 1 : 0;
            #pragma unroll
            for (int off = 1; off < 64; off <<= 1) c += __shfl_xor(c, off);
            if (lane == 0 && my != 0ull && c < KK)
                sidx[c] = (int)(~(uint)(my & 0xFFFFFFFFull));
        }
    } else {
        for (int i = tid; i < ns; i += NT){
            u64 my = keys[i];
            int rank = 0;
            for (int j = 0; j < ns; ++j) rank += (keys[j] > my) ? 1 : 0;
            if (rank < KK) sidx[rank] = (int)(~(uint)(my & 0xFFFFFFFFull));
        }
    }
    __syncthreads();

    if (ns < KK && tid == 0){
        // fallback (unreachable with real data)
        int fill = ns;
        for (int idx = 0; idx < HWW && fill < KK; ++idx){
            bool inCand = false;
            for (int s = 0; s < NSEG && !inCand; ++s){
                const int* pi = ci + (size_t)(b*NSEG + s) * TCAP;
                int c = segc[s];
                for (int i = 0; i < c; ++i) if (pi[i] == idx){ inCand = true; break; }
            }
            if (!inCand) sidx[fill++] = idx;
        }
    }
    __syncthreads();

    // P7: outputs
    if (slice == 0){
        const float* pb = pts + (size_t)b * 4 * HWW;
        float* out0 = out + (size_t)b * KK * 4;
        float* out2 = out + (size_t)(BB * KK * 4 + BB * CC * KK) + (size_t)b * KK * 2;
        for (int k = tid; k < KK; k += NT){
            int idx = sidx[k];
            out0[k * 4 + 0] = pb[idx];
            out0[k * 4 + 1] = pb[HWW + idx];
            out0[k * 4 + 2] = 0.0f;
            out0[k * 4 + 3] = 1.0f;
            out2[k * 2 + 0] = (float)(idx >> 9);
            out2[k * 2 + 1] = (float)(idx & (WW - 1));
        }
    }
    {
        int j = slice * NT + tid;                // 0 .. CC*KK-1
        int c = j >> 9;
        int k = j & (KK - 1);
        float* out1 = out + (size_t)(BB * KK * 4) + (size_t)b * CC * KK;
        out1[j] = feat[(size_t)b * CC * HWW + (size_t)c * HWW + sidx[k]];
    }
}

extern "C" void kernel_launch(void* const* d_in, const int* in_sizes, int n_in,
                              void* d_out, int out_size, void* d_ws, size_t ws_size,
                              hipStream_t stream) {
    const float* s    = (const float*)d_in[0];
    const float* feat = (const float*)d_in[1];
    const float* pts  = (const float*)d_in[2];
    float* out = (float*)d_out;

    char* w = (char*)d_ws;
    float* cs  = (float*)w;  w += (size_t)BB * NSEG * TCAP * 4;
    int*   ci  = (int*)w;    w += (size_t)BB * NSEG * TCAP * 4;
    int*   cnt = (int*)w;    w += (size_t)BB * NSEG * 4;

    nms_fused_k<<<BB * NSEG, NT, 0, stream>>>(s, cs, ci, cnt);
    selgather_k<<<BB * 64, NT, 0, stream>>>(cs, ci, cnt, pts, feat, out);
}

// Round 15
// 54.767 us; speedup vs baseline: 1.2741x; 1.2741x over previous
//
#include <hip/hip_runtime.h>
#include <stdint.h>
#include <math.h>

#define BB 4
#define HH 512
#define WW 512
#define HWW (HH*WW)      // 262144
#define CC 128
#define KK 512
#define SELCAP 2048
#define NBIN 8192
#define NPADK 512

#define TILE 64
#define HALO 15
#define TS 94
#define SWL 104
#define NT 1024
#define TCAP 512
#define NW2 16

typedef unsigned int uint;
typedef unsigned long long u64;

__device__ __forceinline__ float4 ldsf4(const float* p, int o){ return *(const float4*)(p + o); }

#define COLMAX7V(src, o, cm)                                                  \
    { float4 c0=ldsf4(src,(o)-3*SWL), c1=ldsf4(src,(o)-2*SWL), c2=ldsf4(src,(o)-SWL), \
             c3=ldsf4(src,(o)),       c4=ldsf4(src,(o)+SWL),   c5=ldsf4(src,(o)+2*SWL), \
             c6=ldsf4(src,(o)+3*SWL);                                         \
      cm.x=fmaxf(fmaxf(fmaxf(c0.x,c1.x),fmaxf(c2.x,c3.x)),fmaxf(fmaxf(c4.x,c5.x),c6.x)); \
      cm.y=fmaxf(fmaxf(fmaxf(c0.y,c1.y),fmaxf(c2.y,c3.y)),fmaxf(fmaxf(c4.y,c5.y),c6.y)); \
      cm.z=fmaxf(fmaxf(fmaxf(c0.z,c1.z),fmaxf(c2.z,c3.z)),fmaxf(fmaxf(c4.z,c5.z),c6.z)); \
      cm.w=fmaxf(fmaxf(fmaxf(c0.w,c1.w),fmaxf(c2.w,c3.w)),fmaxf(fmaxf(c4.w,c5.w),c6.w)); }

#define ROWMAXV(dst, src, Y0, NROW, G0, NG)                                   \
    for (int i = tid; i < (NROW)*(NG); i += NT){                              \
        int y = (Y0) + i/(NG);                                                \
        int o = y*SWL + (G0) + 4*(i%(NG)) + 4;                                \
        float4 va = ldsf4(src, o-4), vb = ldsf4(src, o), vc = ldsf4(src, o+4);\
        float m2a=fmaxf(va.y,va.z), m2b=fmaxf(va.w,vb.x), m2c=fmaxf(vb.y,vb.z),\
              m2d=fmaxf(vb.w,vc.x), m2e=fmaxf(vc.y,vc.z);                     \
        float4 r;                                                             \
        r.x = fmaxf(fmaxf(m2a,m2b), fmaxf(m2c, vb.w));                        \
        r.y = fmaxf(fmaxf(va.z,m2b), fmaxf(m2c, m2d));                        \
        r.z = fmaxf(fmaxf(m2b,m2c), fmaxf(m2d, vc.y));                        \
        r.w = fmaxf(fmaxf(vb.x,m2c), fmaxf(m2d, m2e));                        \
        *(float4*)((dst) + o) = r;                                            \
    }                                                                         \
    __syncthreads();

#define ROWORV(dst, src, Y0, NROW, G0, NG)                                    \
    for (int i = tid; i < (NROW)*(NG); i += NT){                              \
        int y = (Y0) + i/(NG);                                                \
        int o = y*SWL + (G0) + 4*(i%(NG)) + 4;                                \
        uint u0 = *(const uint*)((src)+o-4), u1 = *(const uint*)((src)+o),    \
             u2 = *(const uint*)((src)+o+4);                                  \
        u64 lo = (u64)u0 | ((u64)u1 << 32);                                   \
        uint r = (uint)(lo>>8) | (uint)(lo>>16) | (uint)(lo>>24) | (uint)(lo>>32) \
               | ((uint)(lo>>40)|(u2<<24)) | ((uint)(lo>>48)|(u2<<16))        \
               | ((uint)(lo>>56)|(u2<<8));                                    \
        *(uint*)((dst)+o) = r;                                                \
    }                                                                         \
    __syncthreads();

#define COLSUPPV(Y0, NROW, G0, NG)                                            \
    for (int i = tid; i < (NROW)*(NG); i += NT){                              \
        int y = (Y0) + i/(NG);                                                \
        int o = y*SWL + (G0) + 4*(i%(NG)) + 4;                                \
        uint v = *(const uint*)(T+o-3*SWL) | *(const uint*)(T+o-2*SWL)        \
               | *(const uint*)(T+o-SWL)   | *(const uint*)(T+o)              \
               | *(const uint*)(T+o+SWL)   | *(const uint*)(T+o+2*SWL)        \
               | *(const uint*)(T+o+3*SWL);                                   \
        *(uint*)(P + o) = v;                                                  \
        float4 s4 = ldsf4(S, o);                                              \
        float4 a;                                                             \
        a.x = (v & 0xffu)       ? 0.0f : s4.x;                                \
        a.y = (v & 0xff00u)     ? 0.0f : s4.y;                                \
        a.z = (v & 0xff0000u)   ? 0.0f : s4.z;                                \
        a.w = (v & 0xff000000u) ? 0.0f : s4.w;                                \
        *(float4*)(A + o) = a;                                                \
    }                                                                         \
    __syncthreads();

// One block = one 64x64 tile (+15 halo). 2-iteration NMS fully in LDS, vectorized 4x.
__global__ __launch_bounds__(NT) void nms_fused_k(const float* __restrict__ sc,
        float* __restrict__ cs, int* __restrict__ ci, int* __restrict__ cnt){
    __shared__ __align__(16) float S[TS*SWL];
    __shared__ __align__(16) float A[TS*SWL];
    __shared__ __align__(16) float Bf[TS*SWL];
    __shared__ __align__(16) unsigned char M[TS*SWL];
    __shared__ __align__(16) unsigned char T[TS*SWL];
    __shared__ __align__(16) unsigned char P[TS*SWL];
    __shared__ float lsc[TCAP];
    __shared__ int   lidx[TCAP];
    __shared__ int   lcnt;

    const int tid = threadIdx.x;
    const int bb = blockIdx.x >> 6;
    const int t  = blockIdx.x & 63;
    const int ty = t >> 3, tx = t & 7;
    const int oy = ty * TILE - HALO, ox = tx * TILE - HALO;
    const float* sb = sc + (size_t)bb * HWW;
    const float QNAN = __int_as_float(0x7fc00000);

    if (tid == 0) lcnt = 0;

    for (int i = tid; i < TS*SWL; i += NT){
        int y = i / SWL, x = i - y*SWL;
        int gy = oy + y, gx = ox + x - 4;
        float v = QNAN;
        if ((unsigned)gy < (unsigned)HH && (unsigned)gx < (unsigned)WW)
            v = sb[(gy << 9) + gx];
        S[i] = v;
    }
    __syncthreads();

    ROWMAXV(A, S, 0, 94, 0, 23)
    for (int i = tid; i < 88*23; i += NT){
        int y = 3 + i/23;
        int o = y*SWL + 4*(i%23) + 4;
        float4 cm; COLMAX7V(A, o, cm);
        float4 s4 = ldsf4(S, o);
        uint m = (s4.x==cm.x ?1u:0u) | (s4.y==cm.y ?0x100u:0u)
               | (s4.z==cm.z ?0x10000u:0u) | (s4.w==cm.w ?0x1000000u:0u);
        *(uint*)(M + o) = m;
    }
    __syncthreads();

    ROWORV(T, M, 3, 88, 4, 21)
    COLSUPPV(6, 82, 4, 21)
    ROWMAXV(Bf, A, 6, 82, 8, 20)
    for (int i = tid; i < 76*20; i += NT){
        int y = 9 + i/20;
        int o = y*SWL + 8 + 4*(i%20) + 4;
        float4 cm; COLMAX7V(Bf, o, cm);
        float4 a4 = ldsf4(A, o);
        uint p4 = *(const uint*)(P+o);
        uint nm = (a4.x==cm.x ?1u:0u)|(a4.y==cm.y ?0x100u:0u)
                | (a4.z==cm.z ?0x10000u:0u)|(a4.w==cm.w ?0x1000000u:0u);
        uint m4 = *(const uint*)(M+o);
        *(uint*)(M+o) = m4 | (nm & ~p4);
    }
    __syncthreads();

    ROWORV(T, M, 9, 76, 12, 18)
    COLSUPPV(12, 70, 12, 18)
    ROWMAXV(Bf, A, 12, 70, 12, 17)

    for (int i = tid; i < 64*17; i += NT){
        int y = 15 + i/17;
        int xg = 12 + 4*(i%17);
        int o = y*SWL + xg + 4;
        float4 cm; COLMAX7V(Bf, o, cm);
        float4 a4 = ldsf4(A, o), s4 = ldsf4(S, o);
        uint p4 = *(const uint*)(P+o), m4 = *(const uint*)(M+o);
        float sa[4] = {s4.x, s4.y, s4.z, s4.w};
        float aa[4] = {a4.x, a4.y, a4.z, a4.w};
        float ca[4] = {cm.x, cm.y, cm.z, cm.w};
        #pragma unroll
        for (int j = 0; j < 4; ++j){
            int x = xg + j;
            bool fm = ((m4 >> (8*j)) & 1u) || ((aa[j]==ca[j]) && !((p4 >> (8*j)) & 1u));
            if ((unsigned)(x - 15) < 64u && fm && sa[j] > 0.0f){
                int p = atomicAdd(&lcnt, 1);
                if (p < TCAP){ lsc[p] = sa[j]; lidx[p] = ((oy+y) << 9) + (ox+x); }
            }
        }
    }
    __syncthreads();

    int nl = lcnt; if (nl > TCAP) nl = TCAP;
    const int seg = bb * 64 + t;
    if (tid == 0) cnt[seg] = nl;
    float* os = cs + (size_t)seg * TCAP;
    int*   oi = ci + (size_t)seg * TCAP;
    for (int i = tid; i < nl; i += NT){ os[i] = lsc[i]; oi[i] = lidx[i]; }
}

// ---------- fused select+gather v3: fixed-point histogram select ----------

__device__ __forceinline__ uint fxbin(float v){
    return ((uint)(v * 8388608.0f)) >> 10;      // v*2^23 exact in f32
}

__global__ __launch_bounds__(NT) void selgather_k(
        const float* __restrict__ cs, const int* __restrict__ ci, const int* __restrict__ cnt,
        const float* __restrict__ pts, const float* __restrict__ feat,
        float* __restrict__ out){
    __shared__ int  hist[NBIN];
    __shared__ __align__(16) u64 keys[SELCAP + 4];
    __shared__ int  segc[64];
    __shared__ int  wsum[16];
    __shared__ int  sidx[KK];
    __shared__ uint sh_Tbits;
    __shared__ int  sh_bin, sh_kneed, sh_n, selCnt, bcnt;

    const int blk = blockIdx.x;
    const int b = blk >> 6, slice = blk & 63;
    const int tid = threadIdx.x;
    const int wv = tid >> 6, lane = tid & 63;

    {
        int4* h4 = (int4*)hist;
        for (int i = tid; i < NBIN/4; i += NT) h4[i] = make_int4(0,0,0,0);
    }
    if (tid < 64){ int c = cnt[b*64 + tid]; segc[tid] = (c > TCAP) ? TCAP : c; }
    if (tid == 0){ selCnt = 0; bcnt = 0; sh_Tbits = 1u; }
    __syncthreads();

    #pragma unroll
    for (int ss = 0; ss < 4; ++ss){
        int s = wv*4 + ss;
        int c = segc[s];
        const float* ps = cs + (size_t)(b*64 + s) * TCAP;
        for (int i = lane; i < c; i += 64)
            atomicAdd(&hist[fxbin(ps[i])], 1);
    }
    __syncthreads();

    int hh[8];
    {
        int4 h0 = *(int4*)&hist[tid*8], h1 = *(int4*)&hist[tid*8 + 4];
        hh[0]=h0.x; hh[1]=h0.y; hh[2]=h0.z; hh[3]=h0.w;
        hh[4]=h1.x; hh[5]=h1.y; hh[6]=h1.z; hh[7]=h1.w;
    }
    int s8 = hh[0]+hh[1]+hh[2]+hh[3]+hh[4]+hh[5]+hh[6]+hh[7];
    int suf = s8;
    #pragma unroll
    for (int off = 1; off < 64; off <<= 1){
        int v = __shfl_down(suf, off);
        if (lane + off < 64) suf += v;
    }
    if (lane == 0) wsum[wv] = suf;
    __syncthreads();
    int W = 0, tot = 0;
    #pragma unroll
    for (int w2 = 0; w2 < 16; ++w2){ int v = wsum[w2]; tot += v; if (w2 > wv) W += v; }
    if (tid == 0) sh_n = tot;
    int G = W + (suf - s8);
    if (tot >= KK && G < KK && G + s8 >= KK){
        int cum = G;
        #pragma unroll
        for (int k = 7; k >= 0; --k){
            if (cum + hh[k] >= KK){ sh_bin = tid*8 + k; sh_kneed = KK - cum; break; }
            cum += hh[k];
        }
    }
    __syncthreads();
    const int n = sh_n;

    uint Tbits = 1u;
    if (n >= KK){
        const int bstar = sh_bin, kneed = sh_kneed;
        #pragma unroll
        for (int ss = 0; ss < 4; ++ss){
            int s = wv*4 + ss;
            int c = segc[s];
            const float* ps = cs + (size_t)(b*64 + s) * TCAP;
            for (int i = lane; i < c; i += 64){
                float v = ps[i];
                if ((int)fxbin(v) == bstar){
                    int p = atomicAdd(&bcnt, 1);
                    if (p < SELCAP) keys[p] = (u64)__float_as_uint(v);
                }
            }
        }
        __syncthreads();
        int m = bcnt; if (m > SELCAP) m = SELCAP;
        if (tid < m){
            u64 mine = keys[tid];
            int gt = 0, ge = 0;
            for (int j = 0; j < m; ++j){
                u64 v = keys[j];
                gt += (v > mine) ? 1 : 0;
                ge += (v >= mine) ? 1 : 0;
            }
            if (gt < kneed && kneed <= ge) sh_Tbits = (uint)mine;
        }
        __syncthreads();
        Tbits = sh_Tbits;
    }

    #pragma unroll
    for (int ss = 0; ss < 4; ++ss){
        int s = wv*4 + ss;
        int c = segc[s];
        const float* ps = cs + (size_t)(b*64 + s) * TCAP;
        const int*   pi = ci + (size_t)(b*64 + s) * TCAP;
        for (int i0 = 0; i0 < c; i0 += 64){
            int i = i0 + lane;
            bool hit = false; uint bits = 0;
            if (i < c){ bits = __float_as_uint(ps[i]); hit = (bits >= Tbits); }
            u64 m = __ballot(hit);
            if (!m) continue;
            int wbase = 0;
            if (lane == 0) wbase = atomicAdd(&selCnt, (int)__popcll(m));
            wbase = __shfl(wbase, 0);
            if (hit){
                int p = wbase + (int)__popcll(m & ((1ull << lane) - 1ull));
                if (p < SELCAP) keys[p] = ((u64)bits << 32) | (uint)(~pi[i]);
            }
        }
    }
    __syncthreads();
    int ns = selCnt; if (ns > SELCAP) ns = SELCAP;
    for (int i = ns + tid; i < NPADK; i += NT) keys[i] = 0ull;
    __syncthreads();

    if (ns <= NPADK){
        u64 ck[8];
        #pragma unroll
        for (int r = 0; r < 8; ++r) ck[r] = keys[r*64 + lane];
        for (int t0 = 0; t0 < 32; ++t0){
            int t = wv*32 + t0;
            u64 my = keys[t];
            int c = 0;
            #pragma unroll
            for (int r = 0; r < 8; ++r) c += (ck[r] > my) ? 1 : 0;
            #pragma unroll
            for (int off = 1; off < 64; off <<= 1) c += __shfl_xor(c, off);
            if (lane == 0 && my != 0ull && c < KK)
                sidx[c] = (int)(~(uint)(my & 0xFFFFFFFFull));
        }
    } else {
        for (int i = tid; i < ns; i += NT){
            u64 my = keys[i];
            int rank = 0;
            for (int j = 0; j < ns; ++j) rank += (keys[j] > my) ? 1 : 0;
            if (rank < KK) sidx[rank] = (int)(~(uint)(my & 0xFFFFFFFFull));
        }
    }
    __syncthreads();

    if (ns < KK && tid == 0){
        int fill = ns;
        for (int idx = 0; idx < HWW && fill < KK; ++idx){
            bool inCand = false;
            for (int s = 0; s < 64 && !inCand; ++s){
                const int* pi = ci + (size_t)(b*64 + s) * TCAP;
                int c = segc[s];
                for (int i = 0; i < c; ++i) if (pi[i] == idx){ inCand = true; break; }
            }
            if (!inCand) sidx[fill++] = idx;
        }
    }
    __syncthreads();

    if (slice == 0){
        const float* pb = pts + (size_t)b * 4 * HWW;
        float* out0 = out + (size_t)b * KK * 4;
        float* out2 = out + (size_t)(BB * KK * 4 + BB * CC * KK) + (size_t)b * KK * 2;
        for (int k = tid; k < KK; k += NT){
            int idx = sidx[k];
            out0[k * 4 + 0] = pb[idx];
            out0[k * 4 + 1] = pb[HWW + idx];
            out0[k * 4 + 2] = 0.0f;
            out0[k * 4 + 3] = 1.0f;
            out2[k * 2 + 0] = (float)(idx >> 9);
            out2[k * 2 + 1] = (float)(idx & (WW - 1));
        }
    }
    {
        int j = slice * NT + tid;
        int c = j >> 9;
        int k = j & (KK - 1);
        float* out1 = out + (size_t)(BB * KK * 4) + (size_t)b * CC * KK;
        out1[j] = feat[(size_t)b * CC * HWW + (size_t)c * HWW + sidx[k]];
    }
}

extern "C" void kernel_launch(void* const* d_in, const int* in_sizes, int n_in,
                              void* d_out, int out_size, void* d_ws, size_t ws_size,
                              hipStream_t stream) {
    const float* s    = (const float*)d_in[0];
    const float* feat = (const float*)d_in[1];
    const float* pts  = (const float*)d_in[2];
    float* out = (float*)d_out;

    char* w = (char*)d_ws;
    float* cs  = (float*)w;  w += (size_t)BB * 64 * TCAP * 4;
    int*   ci  = (int*)w;    w += (size_t)BB * 64 * TCAP * 4;
    int*   cnt = (int*)w;    w += (size_t)BB * 64 * 4;

    nms_fused_k<<<BB * 64, NT, 0, stream>>>(s, cs, ci, cnt);
    selgather_k<<<BB * 64, NT, 0, stream>>>(cs, ci, cnt, pts, feat, out);
}